// Round 2
// baseline (600.757 us; speedup 1.0000x reference)
//
#include <hip/hip_runtime.h>

// Gated SPN, reverse scan over W, h(i,t) = a*x + g1*h(i-1,t+1) + g2*h(i,t+1) + g3*h(i+1,t+1).
//
// 256 blocks: 2 per (b,c) slice, split along H. Each block OWNS 256 rows and
// computes a 16-row halo cone so it can advance WT=16 W-steps independently;
// at tile boundaries the pair exchanges the exact 16-row boundary h-state via
// per-tile global buffers + monotonic atomic flags (reset each launch by a
// captured hipMemsetAsync). LDS forced >80KB so 1 block/CU -> grid 256 == CU
// count: all blocks resident (spin-safe), all 256 CUs pulling HBM.

#define HH 512
#define WW 512
#define WT 16
#define NTILES (WW / WT)
#define ROWS 272          // 256 owned + 16 halo
#define OWNROWS 256
#define HALO 16
#define NT 320            // threads per block (5 waves); threads >= ROWS masked in compute
#define PITCH 273         // float4 pitch of LDS tile (odd -> spread staging banks)

#define NORM_STORE(xx, g1v, g2v, g3v, wl, rr)                                  \
    {                                                                          \
        float sa_ = fabsf(g1v) + fabsf(g2v) + fabsf(g3v);                      \
        float sc_ = (sa_ >= 1.0f) ? (1.0f / sa_) : 1.0f;                       \
        float n1_ = (g1v) * sc_, n2_ = (g2v) * sc_, n3_ = (g3v) * sc_;         \
        float aa_ = 1.0f - n1_ - n2_ - n3_;                                    \
        tile[(wl) * PITCH + (rr)] = make_float4(aa_ * (xx), n1_, n2_, n3_);    \
    }

__global__ __launch_bounds__(NT) void spn_kernel(
    const float* __restrict__ X, const float* __restrict__ G1,
    const float* __restrict__ G2, const float* __restrict__ G3,
    float* __restrict__ OUT, float* __restrict__ PUB, int* __restrict__ FLG)
{
    extern __shared__ char smem[];
    float4* tile = (float4*)smem;                                   // [WT][PITCH]
    float*  hb   = (float*)(smem + (size_t)WT * PITCH * sizeof(float4));
    float* hP = hb;                // state at tile start / even steps
    float* hQ = hb + (ROWS + 2);

    const int tid   = threadIdx.x;
    const int slice = blockIdx.x >> 1;
    const int pos   = blockIdx.x & 1;          // 0: rows 0..271, 1: rows 240..511
    const int rowbase = pos ? (HH - ROWS) : 0; // 0 or 240

    const size_t base = (size_t)slice * (HH * WW) + (size_t)rowbase * WW;
    const float* Xp  = X  + base;
    const float* G1p = G1 + base;
    const float* G2p = G2 + base;
    const float* G3p = G3 + base;
    float* Op = OUT + base;

    // halo exchange plumbing
    float* pub_out = PUB + ((size_t)slice * 2 + pos)       * (NTILES * HALO);
    float* pub_in  = PUB + ((size_t)slice * 2 + (1 - pos)) * (NTILES * HALO);
    int* flg_out = FLG + slice * 2 + pos;
    int* flg_in  = FLG + slice * 2 + (1 - pos);

    // pos==0: publish local rows 240..255, receive into local 256..271
    // pos==1: publish local rows 16..31,  receive into local 0..15
    const bool is_pub  = pos == 0 ? (tid >= 240 && tid < 256) : (tid >= 16 && tid < 32);
    const int  pub_idx = pos == 0 ? tid - 240 : tid - 16;
    const bool is_halo = pos == 0 ? (tid >= 256 && tid < 272) : (tid < 16);
    const int  halo_idx = pos == 0 ? tid - 256 : tid;
    const bool owned   = pos == 0 ? (tid < OWNROWS) : (tid >= HALO && tid < ROWS);
    const bool active  = tid < ROWS;

    // init h lines to zero (state at w = W)
    if (tid < ROWS + 2) { hP[tid] = 0.0f; hQ[tid] = 0.0f; }

    // load geometry: 4 lanes cover one row's 16 floats; 4 rounds cover 320 rows (mask >=272)
    const int lrow0 = tid >> 2;        // + j*80
    const int lq    = tid & 3;

    float4 rx[4], r1[4], r2[4], r3[4];

    {   // prologue: tile 0 (rightmost)
        const int w0 = WW - WT;
        #pragma unroll
        for (int j = 0; j < 4; ++j) {
            if (j == 3 && tid >= 128) continue;   // row would be >= 272
            const size_t off = (size_t)(lrow0 + j * 80) * WW + (size_t)(w0 + lq * 4);
            rx[j] = *(const float4*)(Xp  + off);
            r1[j] = *(const float4*)(G1p + off);
            r2[j] = *(const float4*)(G2p + off);
            r3[j] = *(const float4*)(G3p + off);
        }
    }

    __syncthreads();
    float h = 0.0f;

    for (int t = 0; t < NTILES; ++t) {
        const int w0 = WW - WT * (t + 1);

        // ---- stage regs -> transposed LDS tile ----
        #pragma unroll
        for (int j = 0; j < 4; ++j) {
            if (j == 3 && tid >= 128) continue;
            const int r  = lrow0 + j * 80;
            const int wb = lq * 4;
            NORM_STORE(rx[j].x, r1[j].x, r2[j].x, r3[j].x, wb + 0, r);
            NORM_STORE(rx[j].y, r1[j].y, r2[j].y, r3[j].y, wb + 1, r);
            NORM_STORE(rx[j].z, r1[j].z, r2[j].z, r3[j].z, wb + 2, r);
            NORM_STORE(rx[j].w, r1[j].w, r2[j].w, r3[j].w, wb + 3, r);
        }

        // ---- receive exact halo state for this tile from neighbor ----
        if (t > 0 && is_halo) {
            while (__hip_atomic_load(flg_in, __ATOMIC_ACQUIRE, __HIP_MEMORY_SCOPE_AGENT) < HALO * t) { }
            const float hv = pub_in[(size_t)t * HALO + halo_idx];
            h = hv;
            hP[tid + 1] = hv;
        }

        // ---- issue next tile's global loads (fly during compute) ----
        if (t + 1 < NTILES) {
            const int w0n = w0 - WT;
            #pragma unroll
            for (int j = 0; j < 4; ++j) {
                if (j == 3 && tid >= 128) continue;
                const size_t off = (size_t)(lrow0 + j * 80) * WW + (size_t)(w0n + lq * 4);
                rx[j] = *(const float4*)(Xp  + off);
                r1[j] = *(const float4*)(G1p + off);
                r2[j] = *(const float4*)(G2p + off);
                r3[j] = *(const float4*)(G3p + off);
            }
        }

        __syncthreads();   // tile + halo visible

        // ---- WT steps, w = w0+WT-1 ... w0 ----
        float hout[WT];
        #pragma unroll
        for (int s = 0; s < WT; ++s) {
            const int q = WT - 1 - s;
            const float* hr = (s & 1) ? hQ : hP;
            float*       hw = (s & 1) ? hP : hQ;
            if (active) {
                const float4 v = tile[q * PITCH + tid];
                const float hu = hr[tid];
                const float hd = hr[tid + 2];
                const float hn = fmaf(v.y, hu, fmaf(v.z, h, fmaf(v.w, hd, v.x)));
                hw[tid + 1] = hn;
                h = hn;
                hout[q] = hn;
            }
            __syncthreads();
        }
        // 16 steps (even) -> state for next tile is back in hP

        // ---- publish boundary state_{t+1} for neighbor ----
        if (t + 1 < NTILES && is_pub) {
            pub_out[(size_t)(t + 1) * HALO + pub_idx] = h;
            __threadfence();
            __hip_atomic_fetch_add(flg_out, 1, __ATOMIC_RELAXED, __HIP_MEMORY_SCOPE_AGENT);
        }

        // ---- write owned outputs (contiguous 64B per row) ----
        if (owned) {
            #pragma unroll
            for (int j = 0; j < 4; ++j) {
                const float4 o = make_float4(hout[j * 4 + 0], hout[j * 4 + 1],
                                             hout[j * 4 + 2], hout[j * 4 + 3]);
                *(float4*)(Op + (size_t)tid * WW + (size_t)(w0 + j * 4)) = o;
            }
        }
    }
}

extern "C" void kernel_launch(void* const* d_in, const int* in_sizes, int n_in,
                              void* d_out, int out_size, void* d_ws, size_t ws_size,
                              hipStream_t stream) {
    const float* X  = (const float*)d_in[0];
    const float* G1 = (const float*)d_in[1];
    const float* G2 = (const float*)d_in[2];
    const float* G3 = (const float*)d_in[3];
    float* OUT = (float*)d_out;

    // workspace: per-tile halo buffers + flags
    const size_t pub_floats = (size_t)128 * 2 * NTILES * HALO;   // 128 slices * 2 dirs
    float* PUB = (float*)d_ws;
    int*   FLG = (int*)((char*)d_ws + pub_floats * sizeof(float));

    // reset flags every call (captured as a graph node; keeps launch deterministic)
    hipMemsetAsync(FLG, 0, 256 * sizeof(int), stream);

    const int nblocks = 4 * 32 * 2;   // 2 blocks per slice
    // request 84KB dynamic LDS: forces 1 block/CU -> 256 blocks co-resident on 256 CUs
    const size_t smem = 84 * 1024;

    (void)hipFuncSetAttribute((const void*)spn_kernel,
                              hipFuncAttributeMaxDynamicSharedMemorySize, (int)smem);

    spn_kernel<<<nblocks, NT, smem, stream>>>(X, G1, G2, G3, OUT, PUB, FLG);
}

// Round 3
// 277.386 us; speedup vs baseline: 2.1658x; 2.1658x over previous
//
#include <hip/hip_runtime.h>

// Gated SPN, reverse scan over W (round-1 structure, per-CU overhauled):
//   h(i,t) = a*x + g1*h(i-1,t+1) + g2*h(i,t+1) + g3*h(i+1,t+1), a = 1-g1-g2-g3
// 128 blocks (1 per (b,c) slice), 512 threads (1 per H row), WT=16 col tiles.
// - double reg buffers: next tile's global loads issued FIRST each tile
// - tile staged in LDS with XOR bank swizzle (kills 4-way staging conflicts)
// - h neighbor exchange via __shfl (DPP) + 8 LDS wave-edge slots (parity dbuf)
// - outputs transposed through LDS (reuses consumed tile space) -> coalesced
//   float4 stores (16 rows x 64B per wave-instr instead of 64 scattered txns)

#define HH 512
#define WW 512
#define WT 16
#define NTILES (WW / WT)
#define NT 512

#define SWR(w) (((w) >> 2) & 3)   // row-XOR swizzle per w-slot

struct Regs { float4 x[4], g1[4], g2[4], g3[4]; };

__device__ __forceinline__ void issue_loads(const float* __restrict__ Xp,
                                            const float* __restrict__ G1p,
                                            const float* __restrict__ G2p,
                                            const float* __restrict__ G3p,
                                            int w0, int lrow0, int lq, Regs& R)
{
    #pragma unroll
    for (int j = 0; j < 4; ++j) {
        const size_t off = (size_t)(lrow0 + j * 128) * WW + (size_t)(w0 + lq * 4);
        R.x[j]  = *(const float4*)(Xp  + off);
        R.g1[j] = *(const float4*)(G1p + off);
        R.g2[j] = *(const float4*)(G2p + off);
        R.g3[j] = *(const float4*)(G3p + off);
    }
}

__device__ __forceinline__ void norm_store(float4* __restrict__ tile, int w, int r,
                                           float xx, float g1, float g2, float g3)
{
    const float sa = fabsf(g1) + fabsf(g2) + fabsf(g3);
    const float sc = (sa >= 1.0f) ? (1.0f / sa) : 1.0f;
    const float n1 = g1 * sc, n2 = g2 * sc, n3 = g3 * sc;
    const float a  = 1.0f - n1 - n2 - n3;
    tile[w * HH + (r ^ SWR(w))] = make_float4(a * xx, n1, n2, n3);
}

__device__ __forceinline__ void tile_body(
    int t, Regs& cur, Regs& nxt,
    const float* __restrict__ Xp, const float* __restrict__ G1p,
    const float* __restrict__ G2p, const float* __restrict__ G3p,
    float* __restrict__ Op,
    float4* __restrict__ tile, float* __restrict__ outb, float* __restrict__ edges,
    int tid, int lane, int wv, int lrow0, int lq, float& h)
{
    const int w0 = WW - WT * (t + 1);

    // 1) issue next tile's loads first: VMEM busy across stage+compute
    if (t + 1 < NTILES)
        issue_loads(Xp, G1p, G2p, G3p, w0 - WT, lrow0, lq, nxt);

    // 2) stage current regs -> swizzled LDS tile (normalize once per element)
    #pragma unroll
    for (int j = 0; j < 4; ++j) {
        const int r  = lrow0 + j * 128;
        const int wb = lq * 4;
        norm_store(tile, wb + 0, r, cur.x[j].x, cur.g1[j].x, cur.g2[j].x, cur.g3[j].x);
        norm_store(tile, wb + 1, r, cur.x[j].y, cur.g1[j].y, cur.g2[j].y, cur.g3[j].y);
        norm_store(tile, wb + 2, r, cur.x[j].z, cur.g1[j].z, cur.g2[j].z, cur.g3[j].z);
        norm_store(tile, wb + 3, r, cur.x[j].w, cur.g1[j].w, cur.g2[j].w, cur.g3[j].w);
    }
    __syncthreads();

    // 3) 16 scan steps; h-exchange via DPP shuffles + LDS wave-edge slots
    float hout[WT];
    #pragma unroll
    for (int s = 0; s < WT; ++s) {
        const int q  = WT - 1 - s;
        const int pr = s & 1;
        const float4 v = tile[q * HH + (tid ^ SWR(q))];
        float hu = __shfl_up(h, 1);     // h(i-1) from lane-1
        float hd = __shfl_down(h, 1);   // h(i+1) from lane+1
        if (lane == 0)  hu = edges[(pr * 2 + 1) * 10 + wv];      // R-edge of wave wv-1
        if (lane == 63) hd = edges[(pr * 2 + 0) * 10 + wv + 2];  // L-edge of wave wv+1
        const float hn = fmaf(v.y, hu, fmaf(v.z, h, fmaf(v.w, hd, v.x)));
        if (lane == 0)  edges[((pr ^ 1) * 2 + 0) * 10 + wv + 1] = hn;
        if (lane == 63) edges[((pr ^ 1) * 2 + 1) * 10 + wv + 1] = hn;
        hout[q] = hn;
        h = hn;
        __syncthreads();
    }

    // 4) transpose outputs through LDS (overlaps consumed tile w-slots 0..3)
    #pragma unroll
    for (int w = 0; w < WT; ++w)
        outb[w * HH + tid] = hout[w];
    __syncthreads();

    // 5) coalesced stores: 4 lanes cover one row's 64B, wave covers 16 rows
    #pragma unroll
    for (int j = 0; j < 4; ++j) {
        const int r = lrow0 + j * 128;
        float4 o;
        o.x = outb[(lq * 4 + 0) * HH + r];
        o.y = outb[(lq * 4 + 1) * HH + r];
        o.z = outb[(lq * 4 + 2) * HH + r];
        o.w = outb[(lq * 4 + 3) * HH + r];
        *(float4*)(Op + (size_t)r * WW + (size_t)(w0 + lq * 4)) = o;
    }
    __syncthreads();   // protect outb region before next stage rewrites tile
}

__global__ __launch_bounds__(NT, 2) void spn_kernel(
    const float* __restrict__ X, const float* __restrict__ G1,
    const float* __restrict__ G2, const float* __restrict__ G3,
    float* __restrict__ OUT)
{
    extern __shared__ char smem[];
    float4* tile  = (float4*)smem;            // [WT][HH] granules, row-swizzled
    float*  outb  = (float*)smem;             // overlaps tile w-slots 0..3 (32KB)
    float*  edges = (float*)(smem + (size_t)WT * HH * sizeof(float4)); // [2][2][10]

    const int tid   = threadIdx.x;
    const int lane  = tid & 63;
    const int wv    = tid >> 6;
    const int lrow0 = tid >> 2;
    const int lq    = tid & 3;

    const size_t base = (size_t)blockIdx.x * (size_t)(HH * WW);
    const float* Xp  = X  + base;
    const float* G1p = G1 + base;
    const float* G2p = G2 + base;
    const float* G3p = G3 + base;
    float* Op = OUT + base;

    if (tid < 40) edges[tid] = 0.0f;   // both parities, both kinds, sentinels

    Regs A, B;
    issue_loads(Xp, G1p, G2p, G3p, WW - WT, lrow0, lq, A);
    float h = 0.0f;

    for (int t = 0; t < NTILES; t += 2) {
        tile_body(t,     A, B, Xp, G1p, G2p, G3p, Op, tile, outb, edges,
                  tid, lane, wv, lrow0, lq, h);
        tile_body(t + 1, B, A, Xp, G1p, G2p, G3p, Op, tile, outb, edges,
                  tid, lane, wv, lrow0, lq, h);
    }
}

extern "C" void kernel_launch(void* const* d_in, const int* in_sizes, int n_in,
                              void* d_out, int out_size, void* d_ws, size_t ws_size,
                              hipStream_t stream) {
    const float* X  = (const float*)d_in[0];
    const float* G1 = (const float*)d_in[1];
    const float* G2 = (const float*)d_in[2];
    const float* G3 = (const float*)d_in[3];
    float* OUT = (float*)d_out;

    const int nblocks = 4 * 32;   // one block per (b,c) slice
    const size_t smem = (size_t)WT * HH * sizeof(float4) + 40 * sizeof(float);

    (void)hipFuncSetAttribute((const void*)spn_kernel,
                              hipFuncAttributeMaxDynamicSharedMemorySize, (int)smem);

    spn_kernel<<<nblocks, NT, smem, stream>>>(X, G1, G2, G3, OUT);
}

// Round 4
// 225.821 us; speedup vs baseline: 2.6603x; 1.2283x over previous
//
#include <hip/hip_runtime.h>

// Gated SPN, reverse scan over W:
//   h(i,t) = a*x + g1*h(i-1,t+1) + g2*h(i,t+1) + g3*h(i+1,t+1), a = 1-g1-g2-g3
//
// 128 blocks (1 per (b,c) slice), 1024 threads = 16 waves.
// Per-wave halo cone: wave wv owns rows [32wv, 32wv+32) and computes a 64-row
// cone [32wv-16, 32wv+48). Corruption propagates 1 row/step, so WT=16 scan
// steps need NO barriers and NO LDS h-exchange: neighbors come from DPP
// wave_shr:1 / wave_shl:1 (VALU pipe). Tile carries 16 zero halo rows each
// side (zero BC). At tile end owned lanes publish exact h to an LDS line;
// all lanes refresh from it. 2 barriers/tile instead of ~18.

#define HH 512
#define WW 512
#define WT 16
#define NTILES (WW / WT)
#define NT 1024
#define ROWSP 545            // float4 pitch: 16 halo + 512 + 16 halo + 1 pad
#define HLN 544              // h-line: 16 + 512 + 16

struct Regs { float4 x[2], g1[2], g2[2], g3[2]; };

__device__ __forceinline__ float dpp_prev(float v) {   // lane i <- lane i-1 (wave_shr:1)
    return __int_as_float(__builtin_amdgcn_update_dpp(
        0, __float_as_int(v), 0x138, 0xf, 0xf, false));
}
__device__ __forceinline__ float dpp_next(float v) {   // lane i <- lane i+1 (wave_shl:1)
    return __int_as_float(__builtin_amdgcn_update_dpp(
        0, __float_as_int(v), 0x130, 0xf, 0xf, false));
}

__device__ __forceinline__ void issue_loads(const float* __restrict__ Xp,
                                            const float* __restrict__ G1p,
                                            const float* __restrict__ G2p,
                                            const float* __restrict__ G3p,
                                            int w0, int lrow0, int lq, Regs& R)
{
    #pragma unroll
    for (int j = 0; j < 2; ++j) {
        const size_t off = (size_t)(lrow0 + j * 256) * WW + (size_t)(w0 + lq * 4);
        R.x[j]  = *(const float4*)(Xp  + off);
        R.g1[j] = *(const float4*)(G1p + off);
        R.g2[j] = *(const float4*)(G2p + off);
        R.g3[j] = *(const float4*)(G3p + off);
    }
}

__device__ __forceinline__ void norm_store(float4* __restrict__ tile, int w, int r,
                                           float xx, float g1, float g2, float g3)
{
    const float sa = fabsf(g1) + fabsf(g2) + fabsf(g3);
    const float sc = (sa >= 1.0f) ? (1.0f / sa) : 1.0f;
    const float n1 = g1 * sc, n2 = g2 * sc, n3 = g3 * sc;
    const float a  = 1.0f - n1 - n2 - n3;
    tile[w * ROWSP + (r + 16)] = make_float4(a * xx, n1, n2, n3);
}

__global__ __launch_bounds__(NT, 1) void spn_kernel(
    const float* __restrict__ X, const float* __restrict__ G1,
    const float* __restrict__ G2, const float* __restrict__ G3,
    float* __restrict__ OUT)
{
    extern __shared__ char smem[];
    float4* tile  = (float4*)smem;                                  // [WT][ROWSP]
    float*  hline = (float*)(smem + (size_t)WT * ROWSP * sizeof(float4)); // [HLN]

    const int tid  = threadIdx.x;
    const int wv   = tid >> 6;
    const int lane = tid & 63;
    const int cidx = 32 * wv + lane;        // == cone row + 16, in [0, 544)
    const int row  = 32 * wv + lane - 16;   // cone row in [-16, 528)
    const bool owned = (lane >= 16) && (lane < 48);
    const int lrow0 = tid >> 2;             // load row (2 rounds: +0, +256)
    const int lq    = tid & 3;              // 16B quarter within row

    const size_t base = (size_t)blockIdx.x * (size_t)(HH * WW);
    const float* Xp  = X  + base;
    const float* G1p = G1 + base;
    const float* G2p = G2 + base;
    const float* G3p = G3 + base;
    float* Op = OUT + base;

    // zero halo rows of all w-slots + h-line (one-time; visible after barrier 1)
    if (tid < 256) {
        const int w = tid >> 4, rr = tid & 15;
        tile[w * ROWSP + rr]       = make_float4(0.f, 0.f, 0.f, 0.f);  // rows -16..-1
        tile[w * ROWSP + 528 + rr] = make_float4(0.f, 0.f, 0.f, 0.f);  // rows 512..527
    }
    if (tid < HLN) hline[tid] = 0.0f;

    Regs R;
    issue_loads(Xp, G1p, G2p, G3p, WW - WT, lrow0, lq, R);

    for (int t = 0; t < NTILES; ++t) {
        const int w0 = WW - WT * (t + 1);

        // ---- stage current regs -> LDS tile (normalize once per element) ----
        #pragma unroll
        for (int j = 0; j < 2; ++j) {
            const int r  = lrow0 + j * 256;
            const int wb = lq * 4;
            norm_store(tile, wb + 0, r, R.x[j].x, R.g1[j].x, R.g2[j].x, R.g3[j].x);
            norm_store(tile, wb + 1, r, R.x[j].y, R.g1[j].y, R.g2[j].y, R.g3[j].y);
            norm_store(tile, wb + 2, r, R.x[j].z, R.g1[j].z, R.g2[j].z, R.g3[j].z);
            norm_store(tile, wb + 3, r, R.x[j].w, R.g1[j].w, R.g2[j].w, R.g3[j].w);
        }

        // ---- issue next tile's loads; they fly during the whole scan ----
        if (t + 1 < NTILES)
            issue_loads(Xp, G1p, G2p, G3p, w0 - WT, lrow0, lq, R);

        __syncthreads();   // tile + hline visible

        // ---- 16 barrier-free scan steps on the cone ----
        float h = hline[cidx];     // exact state from previous tile
        float hout[WT];
        #pragma unroll
        for (int s = 0; s < WT; ++s) {
            const int q = WT - 1 - s;
            const float4 v = tile[q * ROWSP + cidx];   // {a*x, g1, g2, g3}
            const float hu = dpp_prev(h);              // h(row-1)
            const float hd = dpp_next(h);              // h(row+1)
            h = fmaf(v.y, hu, fmaf(v.z, h, fmaf(v.w, hd, v.x)));
            hout[q] = h;
        }

        // ---- owned lanes: write outputs + publish exact h ----
        if (owned) {
            #pragma unroll
            for (int j = 0; j < 4; ++j) {
                const float4 o = make_float4(hout[4 * j + 0], hout[4 * j + 1],
                                             hout[4 * j + 2], hout[4 * j + 3]);
                *(float4*)(Op + (size_t)row * WW + (size_t)(w0 + 4 * j)) = o;
            }
            hline[cidx] = h;
        }
        __syncthreads();   // protect tile (rewrite) + hline (read) next iter
    }
}

extern "C" void kernel_launch(void* const* d_in, const int* in_sizes, int n_in,
                              void* d_out, int out_size, void* d_ws, size_t ws_size,
                              hipStream_t stream) {
    const float* X  = (const float*)d_in[0];
    const float* G1 = (const float*)d_in[1];
    const float* G2 = (const float*)d_in[2];
    const float* G3 = (const float*)d_in[3];
    float* OUT = (float*)d_out;

    const int nblocks = 4 * 32;   // one block per (b,c) slice
    const size_t smem = (size_t)WT * ROWSP * sizeof(float4) + HLN * sizeof(float);

    (void)hipFuncSetAttribute((const void*)spn_kernel,
                              hipFuncAttributeMaxDynamicSharedMemorySize, (int)smem);

    spn_kernel<<<nblocks, NT, smem, stream>>>(X, G1, G2, G3, OUT);
}